// Round 4
// baseline (205.127 us; speedup 1.0000x reference)
//
#include <hip/hip_runtime.h>
#include <hip/hip_bf16.h>
#include <cstdint>

typedef __bf16 bf16x8 __attribute__((ext_vector_type(8)));
typedef float f32x4 __attribute__((ext_vector_type(4)));

__device__ __forceinline__ float bf2f(unsigned short u) {
  union { unsigned int i; float f; } x; x.i = ((unsigned int)u) << 16; return x.f;
}
__device__ __forceinline__ unsigned short f2bf(float f) {
  __hip_bfloat16 h = __float2bfloat16(f);
  return __builtin_bit_cast(unsigned short, h);
}

__device__ __forceinline__ void gload_lds16(const void* g, void* l) {
  auto gp = reinterpret_cast<__attribute__((address_space(1))) char*>(
      reinterpret_cast<uintptr_t>(g));
  auto lp = reinterpret_cast<__attribute__((address_space(3))) char*>(
      reinterpret_cast<uintptr_t>(l));
  __builtin_amdgcn_global_load_lds(gp, lp, 16, 0, 0);
}

#define SB() __builtin_amdgcn_sched_barrier(0)
#define BAR()                         \
  do {                                \
    SB();                             \
    __builtin_amdgcn_s_barrier();     \
    SB();                             \
  } while (0)
#define LGKM0()                                          \
  do {                                                   \
    asm volatile("s_waitcnt lgkmcnt(0)" ::: "memory");   \
    SB();                                                \
  } while (0)

// T1: bijective XCD-aware block swizzle (requires total blocks % 8 == 0)
__device__ __forceinline__ void xcd_swz(int& bx, int& by, int& bz) {
  const int gx = gridDim.x, gy = gridDim.y;
  const int n = gx * gy * (int)gridDim.z;
  int lin = blockIdx.x + gx * (blockIdx.y + gy * blockIdx.z);
  lin = (lin & 7) * (n >> 3) + (lin >> 3);
  bx = lin % gx; lin /= gx;
  by = lin % gy; bz = lin / gy;
}

// ---------- fp32 -> bf16 ----------
__global__ __launch_bounds__(256) void cvt_f32_to_bf16(
    const float* __restrict__ in, unsigned short* __restrict__ out, long n4) {
  long i = (long)blockIdx.x * 256 + threadIdx.x;
  if (i >= n4) return;
  const float4 v = reinterpret_cast<const float4*>(in)[i];
  ushort4 o;
  o.x = f2bf(v.x); o.y = f2bf(v.y); o.z = f2bf(v.z); o.w = f2bf(v.w);
  reinterpret_cast<ushort4*>(out)[i] = o;
}

// ---------- all 4 weight transposes in one launch ----------
__global__ void transpose_w4(const float* __restrict__ w0,
                             const float* __restrict__ w1,
                             const float* __restrict__ w2,
                             const float* __restrict__ w3,
                             unsigned short* __restrict__ out) {
  const int z = blockIdx.z;
  const float* in = (z == 0) ? w0 : (z == 1) ? w1 : (z == 2) ? w2 : w3;
  out += (size_t)z * 1024 * 1024;
  __shared__ float tile[32][33];
  const int c0 = blockIdx.x * 32, r0 = blockIdx.y * 32;
  tile[threadIdx.y][threadIdx.x] =
      in[(size_t)(r0 + threadIdx.y) * 1024 + c0 + threadIdx.x];
  __syncthreads();
  out[(size_t)(c0 + threadIdx.y) * 1024 + r0 + threadIdx.x] =
      f2bf(tile[threadIdx.x][threadIdx.y]);
}

__global__ void concat_bias3(const float* a, const float* b, const float* c,
                             float* o) {
  int i = blockIdx.x * 256 + threadIdx.x;
  if (i >= 3072) return;
  o[i] = (i < 1024) ? a[i] : (i < 2048 ? b[i - 1024] : c[i - 2048]);
}

// ===== shared staging / frag macros (XOR swizzle: both-sides involution) =====
#define STAGE128(gbase, ld, ldsbase, rowbase)                                 \
  {                                                                           \
    _Pragma("unroll") for (int l_ = 0; l_ < 2; ++l_) {                        \
      const int seg_ = (w << 1) + l_;                                         \
      const int r0_ = (rowbase) + (seg_ << 3);                                \
      const int gr_ = r0_ + (lane >> 3);                                      \
      const int sc_ = ((lane & 7) ^ (lane >> 3)) << 3;                        \
      gload_lds16((gbase) + (size_t)gr_ * (ld) + sc_, (ldsbase) + r0_ * 64);  \
    }                                                                         \
  }

#define LDA_FRAG(dst, tile, rbase)                                            \
  _Pragma("unroll") for (int m_ = 0; m_ < 4; ++m_)                            \
  _Pragma("unroll") for (int kk_ = 0; kk_ < 2; ++kk_) {                       \
    const int row_ = (rbase) + (m_ << 4) + (lane & 15);                       \
    const int ch_ = ((kk_ << 2) + (lane >> 4)) ^ (lane & 7);                  \
    dst[m_][kk_] =                                                            \
        *reinterpret_cast<const bf16x8*>((tile) + row_ * 64 + (ch_ << 3));    \
  }
#define LDB_FRAG(dst, tile, rbase)                                            \
  _Pragma("unroll") for (int n_ = 0; n_ < 2; ++n_)                            \
  _Pragma("unroll") for (int kk_ = 0; kk_ < 2; ++kk_) {                       \
    const int row_ = (rbase) + (n_ << 4) + (lane & 15);                       \
    const int ch_ = ((kk_ << 2) + (lane >> 4)) ^ (lane & 7);                  \
    dst[n_][kk_] =                                                            \
        *reinterpret_cast<const bf16x8*>((tile) + row_ * 64 + (ch_ << 3));    \
  }

// =====================================================================
// gemm256: 256x256 tile, 8 waves (2M x 4N), 8-phase (m201 template).
// Used for scores (within-run A/B reference schedule).
// =====================================================================
#define STAGE_A(gbase, ld, ldsbase, h)                                        \
  {                                                                           \
    _Pragma("unroll") for (int l_ = 0; l_ < 2; ++l_) {                        \
      const int seg_ = (w << 1) + l_;                                         \
      const int r0_ = ((seg_ >> 3) << 7) + ((h) << 6) + ((seg_ & 7) << 3);    \
      const int gr_ = r0_ + (lane >> 3);                                      \
      const int sc_ = ((lane & 7) ^ (lane >> 3)) << 3;                        \
      gload_lds16((gbase) + (size_t)gr_ * (ld) + sc_, (ldsbase) + r0_ * 64);  \
    }                                                                         \
  }
#define STAGE_B(gbase, ld, ldsbase, h)                                        \
  {                                                                           \
    _Pragma("unroll") for (int l_ = 0; l_ < 2; ++l_) {                        \
      const int seg_ = (w << 1) + l_;                                         \
      const int r0_ = ((seg_ >> 2) << 6) + ((h) << 5) + ((seg_ & 3) << 3);    \
      const int gr_ = r0_ + (lane >> 3);                                      \
      const int sc_ = ((lane & 7) ^ (lane >> 3)) << 3;                        \
      gload_lds16((gbase) + (size_t)gr_ * (ld) + sc_, (ldsbase) + r0_ * 64);  \
    }                                                                         \
  }

#define MFMA_QUAD(a_, b_, af_, bf_)                                           \
  __builtin_amdgcn_s_setprio(1);                                              \
  _Pragma("unroll") for (int m_ = 0; m_ < 4; ++m_)                            \
  _Pragma("unroll") for (int n_ = 0; n_ < 2; ++n_)                            \
  _Pragma("unroll") for (int kk_ = 0; kk_ < 2; ++kk_)                         \
      acc[(a_) * 4 + m_][(b_) * 2 + n_] =                                     \
          __builtin_amdgcn_mfma_f32_16x16x32_bf16(                            \
              af_[m_][kk_], bf_[n_][kk_], acc[(a_) * 4 + m_][(b_) * 2 + n_],  \
              0, 0, 0);                                                       \
  __builtin_amdgcn_s_setprio(0);

template <typename OutT, bool HAS_BIAS>
__global__ __launch_bounds__(512, 2) void gemm256(
    const unsigned short* __restrict__ A,
    const unsigned short* __restrict__ Bt,
    OutT* __restrict__ C,
    const float* __restrict__ bias,
    int K, int lda, int ldb, int ldc, float scale,
    long sA, long sB, long sC) {
  int bx, by, bz;
  xcd_swz(bx, by, bz);
  A  += (long)bz * sA;
  Bt += (long)bz * sB;
  C  += (long)bz * sC;
  const int n0 = bx << 8;
  const int m0 = by << 8;
  __shared__ __attribute__((aligned(16))) unsigned short lds[2 * 32768];
  const int t = threadIdx.x;
  const int lane = t & 63;
  const int w = t >> 6;
  const int wm = w >> 2, wn = w & 3;
  const unsigned short* gA = A + (size_t)m0 * lda;
  const unsigned short* gB = Bt + (size_t)n0 * ldb;
  const int NT = K >> 6;

  f32x4 acc[8][4];
  const f32x4 vz = {0.f, 0.f, 0.f, 0.f};
#pragma unroll
  for (int i = 0; i < 8; ++i)
#pragma unroll
    for (int j = 0; j < 4; ++j) acc[i][j] = vz;

  {
    unsigned short* a0 = lds;
    unsigned short* b0t = lds + 16384;
    STAGE_A(gA, lda, a0, 0);
    STAGE_B(gB, ldb, b0t, 0);
    STAGE_B(gB, ldb, b0t, 1);
    STAGE_A(gA, lda, a0, 1);
    if (NT > 1) {
      unsigned short* a1 = lds + 32768;
      unsigned short* b1t = lds + 32768 + 16384;
      STAGE_A(gA + 64, lda, a1, 0);
      STAGE_B(gB + 64, ldb, b1t, 0);
      STAGE_B(gB + 64, ldb, b1t, 1);
      asm volatile("s_waitcnt vmcnt(6)" ::: "memory");
    } else {
      asm volatile("s_waitcnt vmcnt(0)" ::: "memory");
    }
  }
  BAR();

  for (int kt = 0; kt < NT; ++kt) {
    unsigned short* at = lds + ((kt & 1) << 15);
    unsigned short* bt = at + 16384;
    unsigned short* atN = lds + (((kt + 1) & 1) << 15);
    const unsigned short* gA1 = gA + (size_t)(kt + 1) * 64;
    const unsigned short* gA2 = gA + (size_t)(kt + 2) * 64;
    const unsigned short* gB2 = gB + (size_t)(kt + 2) * 64;
    const bool st1 = kt + 1 < NT, st2 = kt + 2 < NT;

    bf16x8 af[4][2], b0[2][2], b1[2][2];

    LDA_FRAG(af, at, (wm << 7));
    LDB_FRAG(b0, bt, (wn << 6));
    if (st1) STAGE_A(gA1, lda, atN, 1);
    BAR();
    LGKM0();
    MFMA_QUAD(0, 0, af, b0);
    BAR();

    LDB_FRAG(b1, bt, (wn << 6) + 32);
    if (st2) STAGE_A(gA2, lda, at, 0);
    BAR();
    LGKM0();
    MFMA_QUAD(0, 1, af, b1);
    BAR();

    LDA_FRAG(af, at, (wm << 7) + 64);
    if (st2) STAGE_B(gB2, ldb, bt, 0);
    BAR();
    LGKM0();
    MFMA_QUAD(1, 0, af, b0);
    BAR();

    if (st2) STAGE_B(gB2, ldb, bt, 1);
    if (kt < NT - 3) {
      asm volatile("s_waitcnt vmcnt(6)" ::: "memory");
    } else {
      asm volatile("s_waitcnt vmcnt(0)" ::: "memory");
    }
    BAR();
    MFMA_QUAD(1, 1, af, b1);
    BAR();
  }

  const int crow0 = m0 + (wm << 7) + ((lane >> 4) << 2);
  const int ccol0 = n0 + (wn << 6) + (lane & 15);
#pragma unroll
  for (int mf = 0; mf < 8; ++mf) {
#pragma unroll
    for (int nf = 0; nf < 4; ++nf) {
      const int col = ccol0 + (nf << 4);
      const float bb = HAS_BIAS ? bias[col] : 0.f;
#pragma unroll
      for (int i = 0; i < 4; ++i) {
        const int row = crow0 + (mf << 4) + i;
        const float v = acc[mf][nf][i] * scale + bb;
        if constexpr (sizeof(OutT) == 2) {
          C[(size_t)row * ldc + col] = (OutT)f2bf(v);
        } else {
          C[(size_t)row * ldc + col] = (OutT)v;
        }
      }
    }
  }
}

// =====================================================================
// gemm128t: BM=256 x BN=128, 8 waves (4M x 2N), per-wave 64x64, acc[4][4].
// TRIPLE-buffered LDS (3 x 48KB = 144KB), distance-2 tile prefetch:
// at tile t, P1 stages A(t+2), P2 stages B(t+2) into buf[(t+2)%3], whose
// last reader (tile t-1) fully drained behind two barriers -> race-free.
// One counted vmcnt(6)/tile (= 6 loads of t+2 in flight; all t+1 landed).
// VSPLIT: blocks with n0>=2048 write V transposed to vt[b][d][s].
// =====================================================================
#define MFMA_QUAD128(b_, af_, bf_)                                            \
  __builtin_amdgcn_s_setprio(1);                                              \
  _Pragma("unroll") for (int m_ = 0; m_ < 4; ++m_)                            \
  _Pragma("unroll") for (int n_ = 0; n_ < 2; ++n_)                            \
  _Pragma("unroll") for (int kk_ = 0; kk_ < 2; ++kk_)                         \
      acc[m_][(b_) * 2 + n_] = __builtin_amdgcn_mfma_f32_16x16x32_bf16(       \
          af_[m_][kk_], bf_[n_][kk_], acc[m_][(b_) * 2 + n_], 0, 0, 0);       \
  __builtin_amdgcn_s_setprio(0);

template <typename OutT, bool HAS_BIAS, bool VSPLIT>
__global__ __launch_bounds__(512, 2) void gemm128t(
    const unsigned short* __restrict__ A,
    const unsigned short* __restrict__ Bt,
    OutT* __restrict__ C,
    const float* __restrict__ bias,
    unsigned short* __restrict__ vt,
    int K, int lda, int ldb, int ldc, float scale,
    long sA, long sB, long sC) {
  int bx, by, bz;
  xcd_swz(bx, by, bz);
  A  += (long)bz * sA;
  Bt += (long)bz * sB;
  C  += (long)bz * sC;
  const int n0 = bx << 7;
  const int m0 = by << 8;
  __shared__ __attribute__((aligned(16))) unsigned short lds[3 * 24576];
  const int t = threadIdx.x;
  const int lane = t & 63;
  const int w = t >> 6;
  const int wm = w >> 1, wn = w & 1;
  const unsigned short* gA = A + (size_t)m0 * lda;
  const unsigned short* gB = Bt + (size_t)n0 * ldb;
  const int NT = K >> 6;  // >= 3 for all uses here

  f32x4 acc[4][4];
  const f32x4 vz = {0.f, 0.f, 0.f, 0.f};
#pragma unroll
  for (int i = 0; i < 4; ++i)
#pragma unroll
    for (int j = 0; j < 4; ++j) acc[i][j] = vz;

  // prologue: stage tile0 + tile1 (12 loads); vmcnt(6) -> tile0 landed
  {
    STAGE128(gA, lda, lds, 0);
    STAGE128(gA, lda, lds, 128);
    STAGE128(gB, ldb, lds + 16384, 0);
    STAGE128(gA + 64, lda, lds + 24576, 0);
    STAGE128(gA + 64, lda, lds + 24576, 128);
    STAGE128(gB + 64, ldb, lds + 24576 + 16384, 0);
    asm volatile("s_waitcnt vmcnt(6)" ::: "memory");
  }
  BAR();

  int idx = 0;  // kt % 3
  for (int kt = 0; kt < NT; ++kt) {
    unsigned short* at = lds + idx * 24576;
    unsigned short* btile = at + 16384;
    int idx2 = idx + 2; if (idx2 >= 3) idx2 -= 3;
    unsigned short* st = lds + idx2 * 24576;
    const unsigned short* gA2 = gA + (size_t)(kt + 2) * 64;
    const unsigned short* gB2 = gB + (size_t)(kt + 2) * 64;
    const bool st2 = kt + 2 < NT;

    bf16x8 af[4][2], b0[2][2], b1[2][2];

    // P1: read A(t) (8) + B-half0(t) (4); stage A(t+2)
    LDA_FRAG(af, at, (wm << 6));
    LDB_FRAG(b0, btile, (wn << 6));
    if (st2) {
      STAGE128(gA2, lda, st, 0);
      STAGE128(gA2, lda, st, 128);
    }
    BAR();
    LGKM0();
    MFMA_QUAD128(0, af, b0);
    BAR();

    // P2: read B-half1(t) (4); stage B(t+2); one counted vmcnt per tile
    LDB_FRAG(b1, btile, (wn << 6) + 32);
    if (st2) STAGE128(gB2, ldb, st + 16384, 0);
    if (kt < NT - 2) {
      asm volatile("s_waitcnt vmcnt(6)" ::: "memory");
    } else {
      asm volatile("s_waitcnt vmcnt(0)" ::: "memory");
    }
    BAR();
    LGKM0();
    MFMA_QUAD128(1, af, b1);
    BAR();

    idx = (idx + 1 == 3) ? 0 : idx + 1;
  }

  const int crow0 = m0 + (wm << 6) + ((lane >> 4) << 2);
  const int ccol0 = n0 + (wn << 6) + (lane & 15);

  if (VSPLIT && n0 >= 2048) {
    const int b = m0 >> 11;
#pragma unroll
    for (int mf = 0; mf < 4; ++mf) {
#pragma unroll
      for (int nf = 0; nf < 4; ++nf) {
        const int col = ccol0 + (nf << 4);
        const float bb = HAS_BIAS ? bias[col] : 0.f;
        const int d = col - 2048;
        const int s = (crow0 & 2047) + (mf << 4);
        ushort4 o;
        o.x = f2bf(acc[mf][nf][0] * scale + bb);
        o.y = f2bf(acc[mf][nf][1] * scale + bb);
        o.z = f2bf(acc[mf][nf][2] * scale + bb);
        o.w = f2bf(acc[mf][nf][3] * scale + bb);
        *reinterpret_cast<ushort4*>(vt + (((size_t)b << 10) + d) * 2048 + s) = o;
      }
    }
    return;
  }

#pragma unroll
  for (int mf = 0; mf < 4; ++mf) {
#pragma unroll
    for (int nf = 0; nf < 4; ++nf) {
      const int col = ccol0 + (nf << 4);
      const float bb = HAS_BIAS ? bias[col] : 0.f;
#pragma unroll
      for (int i = 0; i < 4; ++i) {
        const int row = crow0 + (mf << 4) + i;
        const float v = acc[mf][nf][i] * scale + bb;
        if constexpr (sizeof(OutT) == 2) {
          C[(size_t)row * ldc + col] = (OutT)f2bf(v);
        } else {
          C[(size_t)row * ldc + col] = (OutT)v;
        }
      }
    }
  }
}

// ---------- row softmax, in place, bf16, one block per row ----------
__global__ __launch_bounds__(256) void softmax_inplace(
    unsigned short* __restrict__ P, int S) {
  const size_t row = blockIdx.x;
  unsigned short* p = P + row * (size_t)S;
  const int t = threadIdx.x;
  const int lane = t & 63, w = t >> 6;
  const uint4 raw = reinterpret_cast<const uint4*>(p)[t];
  unsigned int u[4] = {raw.x, raw.y, raw.z, raw.w};
  float v[8];
#pragma unroll
  for (int j = 0; j < 4; ++j) {
    v[2 * j]     = bf2f((unsigned short)(u[j] & 0xffffu));
    v[2 * j + 1] = bf2f((unsigned short)(u[j] >> 16));
  }
  float mx = v[0];
#pragma unroll
  for (int j = 1; j < 8; ++j) mx = fmaxf(mx, v[j]);
#pragma unroll
  for (int off = 32; off >= 1; off >>= 1) mx = fmaxf(mx, __shfl_xor(mx, off, 64));
  __shared__ float red[4];
  if (lane == 0) red[w] = mx;
  __syncthreads();
  mx = fmaxf(fmaxf(red[0], red[1]), fmaxf(red[2], red[3]));
  float e[8];
  float s = 0.f;
#pragma unroll
  for (int j = 0; j < 8; ++j) { e[j] = __expf(v[j] - mx); s += e[j]; }
#pragma unroll
  for (int off = 32; off >= 1; off >>= 1) s += __shfl_xor(s, off, 64);
  __syncthreads();
  if (lane == 0) red[w] = s;
  __syncthreads();
  s = red[0] + red[1] + red[2] + red[3];
  const float inv = 1.f / s;
  unsigned int o[4];
#pragma unroll
  for (int j = 0; j < 4; ++j)
    o[j] = (unsigned int)f2bf(e[2 * j] * inv) |
           ((unsigned int)f2bf(e[2 * j + 1] * inv) << 16);
  uint4 ov; ov.x = o[0]; ov.y = o[1]; ov.z = o[2]; ov.w = o[3];
  reinterpret_cast<uint4*>(p)[t] = ov;
}

// ---------- launch ----------
extern "C" void kernel_launch(void* const* d_in, const int* in_sizes, int n_in,
                              void* d_out, int out_size, void* d_ws, size_t ws_size,
                              hipStream_t stream) {
  (void)in_sizes; (void)n_in; (void)out_size; (void)ws_size;
  const float* x  = (const float*)d_in[0];
  const float* Wq = (const float*)d_in[1];
  const float* bq = (const float*)d_in[2];
  const float* Wk = (const float*)d_in[3];
  const float* bk = (const float*)d_in[4];
  const float* Wv = (const float*)d_in[5];
  const float* bv = (const float*)d_in[6];
  const float* Wo = (const float*)d_in[7];
  const float* bo = (const float*)d_in[8];
  float* out = (float*)d_out;

  constexpr int B = 4, S = 2048, D = 1024;
  constexpr long BS = (long)B * S;  // 8192
  constexpr size_t MB = 1ull << 20;
  char* ws = (char*)d_ws;
  unsigned short* xb   = (unsigned short*)(ws + 0);        // 16MB (dead after QKV)
  unsigned short* Wall = (unsigned short*)(ws + 16 * MB);  // 8MB [4][1024][1024]
  float*          bqkv = (float*)(ws + 24 * MB);           // 12KB
  unsigned short* QKVc = (unsigned short*)(ws + 25 * MB);  // 32MB [8192][2048] (Q|K)
  unsigned short* Vt   = (unsigned short*)(ws + 57 * MB);  // 16MB [4][1024][2048]
  unsigned short* Sc   = (unsigned short*)(ws + 73 * MB);  // 32MB
  unsigned short* AO   = (unsigned short*)(ws + 0);        // 16MB (over xb)

  const float scale = 0.03125f;  // 1/sqrt(1024)

  cvt_f32_to_bf16<<<(BS * D / 4 + 255) / 256, 256, 0, stream>>>(x, xb, BS * D / 4);
  transpose_w4<<<dim3(32, 32, 4), dim3(32, 32), 0, stream>>>(Wq, Wk, Wv, Wo, Wall);
  concat_bias3<<<12, 256, 0, stream>>>(bq, bk, bv, bqkv);

  // fused QKV projection (triple-buffered): Q|K -> QKVc, V -> Vt transposed
  gemm128t<unsigned short, true, true><<<dim3(24, 32, 1), 512, 0, stream>>>(
      xb, Wall, QKVc, bqkv, Vt, D, D, D, 2048, 1.f, 0, 0, 0);

  // scores[b] = scale * Q[b] @ K[b]^T  (gemm256 reference schedule)
  gemm256<unsigned short, false><<<dim3(S / 256, S / 256, B), 512, 0, stream>>>(
      QKVc + 0, QKVc + 1024, Sc, nullptr, D, 2048, 2048, S, scale,
      (long)S * 2048, (long)S * 2048, (long)S * S);

  softmax_inplace<<<B * S, 256, 0, stream>>>(Sc, S);

  // attn_out[b] = P[b] @ V[b] via Vt: M=2048, N=1024, K=2048
  gemm128t<unsigned short, false, false><<<dim3(8, 8, 4), 512, 0, stream>>>(
      Sc, Vt, AO, nullptr, nullptr, S, S, S, D, 1.f,
      (long)S * S, (long)D * S, (long)S * D);

  // out = AO @ Wot^T + bo (fp32), M=8192, N=1024
  gemm128t<float, true, false><<<dim3(8, 32, 1), 512, 0, stream>>>(
      AO, Wall + 3 * 1024 * 1024, out, bo, nullptr, D, D, D, D, 1.f, 0, 0, 0);
}